// Round 14
// baseline (362.843 us; speedup 1.0000x reference)
//
#include <hip/hip_runtime.h>
#include <hip/hip_bf16.h>
#include <stdint.h>

#define G_ 8
#define T_ 1024
#define K_ 7168
#define N_ 2048
#define KB_ 56         // K/128 quant blocks
#define NB_ 16         // N/128
#define NT8_ 56        // K-tiles of 128
#define NV_ 28         // barrier intervals per tile (2 K-tiles each)

#define ACT_WGS  57344   // (G*T*KB)/8
#define WREC_WGS 28672   // (G*N*K/16)/256

typedef __attribute__((ext_vector_type(4))) float f32x4;
typedef __attribute__((ext_vector_type(8))) int   i32x8;

typedef __attribute__((address_space(3))) uint32_t lds_u32_t;
typedef const __attribute__((address_space(1))) uint32_t gbl_u32_t;

__device__ __forceinline__ void gload_lds16(const void* gsrc, const void* ldst)
{
    __builtin_amdgcn_global_load_lds(
        (gbl_u32_t*)(uintptr_t)gsrc,
        (lds_u32_t*)(uint32_t)(uintptr_t)ldst, 16, 0, 0);
}

__device__ __forceinline__ void blockbar()
{
    asm volatile("" ::: "memory");
    __builtin_amdgcn_s_barrier();
    asm volatile("" ::: "memory");
}

// ---------------------------------------------------------------------------
// Kernel 1: fused prepass (verified rounds 6-13).
// ---------------------------------------------------------------------------
__global__ __launch_bounds__(256) void prep_kernel(
    const float* __restrict__ xs, uint8_t* __restrict__ xq8,
    float* __restrict__ ascale,
    const float* __restrict__ w, uint8_t* __restrict__ wq8)
{
    const int bid = blockIdx.x;
    const int tid = threadIdx.x;
    if (bid < ACT_WGS) {
        const int grp = (bid * 256 + tid) >> 5;
        const int l   = tid & 31;
        const size_t base = (size_t)grp * 128 + (size_t)l * 4;

        const float4 v = *(const float4*)(xs + base);
        float am = fmaxf(fmaxf(fabsf(v.x), fabsf(v.y)),
                         fmaxf(fabsf(v.z), fabsf(v.w)));
#pragma unroll
        for (int off = 1; off <= 16; off <<= 1)
            am = fmaxf(am, __shfl_xor(am, off, 64));

        const float rs = 448.0f / am;
        const float s  = am * (1.0f / 448.0f);

        int pk = __builtin_amdgcn_cvt_pk_fp8_f32(v.x * rs, v.y * rs, 0, false);
        pk     = __builtin_amdgcn_cvt_pk_fp8_f32(v.z * rs, v.w * rs, pk, true);
        *(uint32_t*)(xq8 + base) = (uint32_t)pk;

        if (l == 0) {
            const int kb = grp % KB_;
            const int t  = (grp / KB_) & (T_ - 1);
            const int g  = grp / (KB_ * T_);
            ascale[(((size_t)(g * 4 + (t >> 8))) * KB_ + kb) * 256 + (t & 255)] = s;
        }
    } else {
        const size_t i = ((size_t)(bid - ACT_WGS) * 256 + tid) * 16;
        uint32_t o[4];
#pragma unroll
        for (int q = 0; q < 4; ++q) {
            const float4 a = *(const float4*)(w + i + q * 4);
            int pk = __builtin_amdgcn_cvt_pk_fp8_f32(a.x, a.y, 0, false);
            pk     = __builtin_amdgcn_cvt_pk_fp8_f32(a.z, a.w, pk, true);
            o[q] = (uint32_t)pk;
        }
        *(uint4*)(wq8 + i) = make_uint4(o[0], o[1], o[2], o[3]);
    }
}

// ---------------------------------------------------------------------------
// Kernel 2: persistent producer/consumer blockwise-fp8 grouped GEMM.
//   Grid 256 (1 block/CU), 512 threads. Each block: fixed (g, tn), loops
//   4 tm-tiles (tm = j + 2t). Waves 0-3 consumers, 4-7 producers.
//   Interval = 2 K-tiles (32 MFMA): buf for k-tile u is u&3 (pair v&1).
//   Producer at interval v stages k-tiles 2v+2, 2v+3 into the other pair,
//   then vmcnt(0) (flight = 1 interval ~1400cyc > HBM latency -> no stall).
//   LDS: A 4x16K @0 | B 4x16K @65536 | ascale 2x4K @131072 | wscale @139264.
// ---------------------------------------------------------------------------
union Frag { i32x8 v; struct { int4 lo, hi; } p; };

#define RD_FRAG(dst, base, r)                                                 \
  { const int rx_ = ((r) & 7) << 4;                                           \
    const char* bp_ = smem + (base) + (r)*128;                                \
    dst.p.lo = *(const int4*)(bp_ + ((lhi*32) ^ rx_));                        \
    dst.p.hi = *(const int4*)(bp_ + ((lhi*32 + 16) ^ rx_)); }

#define STG_A(c, t, bb) gload_lds16(pA8[c] + (size_t)(t)*128,                 \
      smem + (bb)*16384 + (c)*4096 + ptid*16)
#define STG_B(c, t, bb) gload_lds16(pB8[c] + (size_t)(t)*128,                 \
      smem + 65536 + (bb)*16384 + (c)*4096 + ptid*16)
#define STG_S(c) gload_lds16(pS + (size_t)(c)*2048,                           \
      smem + 131072 + ((c)&1)*4096 + ptid*16)

__global__ __launch_bounds__(512, 1) void gemm_fp8_kernel(
    const uint8_t* __restrict__ xq8, const uint8_t* __restrict__ wq8,
    const float* __restrict__ ascale, const float* __restrict__ wscale,
    const float* __restrict__ bias, float* __restrict__ y)
{
    __shared__ char smem[139520];

    const int bx0 = blockIdx.x;          // 0..255
    const int g     = bx0 & 7;           // group == XCD
    const int inner = bx0 >> 3;          // 0..31
    const int tn    = inner >> 1;        // 0..15 (fixed per block)
    const int jj    = inner & 1;         // tm parity class
    const int n0    = tn * 128;

    const int tid  = threadIdx.x, lane = tid & 63, wid = tid >> 6;
    const bool producer = (wid >= 4);
    const int ptid = tid & 255;
    const int l15 = lane & 15, lhi = lane >> 4;
    const int wrow = (wid >> 1) * 64;    // consumer quadrant (wid 0..3)
    const int wcol = (wid & 1) * 64;

    const uint8_t* Ag = xq8 + (size_t)g * T_ * K_;
    const uint8_t* Bg = wq8 + (size_t)g * N_ * K_;

    const int srow = ptid >> 3;
    const int xoff = ((ptid & 7) ^ (srow & 7)) * 16;
    const uint8_t* pB8[4];
#pragma unroll
    for (int c = 0; c < 4; ++c)
        pB8[c] = Bg + (size_t)(n0 + c * 32 + srow) * K_ + xoff;

    const f32x4 z4 = {0.f, 0.f, 0.f, 0.f};
    Frag bF[4];
    f32x4 asv[4];

    // ---- block prologue: wscale row (same tn for all 4 tiles) ----
    if (producer) {
        if (ptid < KB_) {
            const float wv = wscale[((size_t)(g * NB_ + tn)) * KB_ + ptid];
            *(float*)(smem + 139264 + ptid * 4) = wv;
        }
    } else {
        __builtin_amdgcn_s_setprio(1);
    }

    for (int tt = 0; tt < 4; ++tt) {
        const int tm = jj + 2 * tt;
        const int t0 = tm * 128;

        const uint8_t* pA8[4];
#pragma unroll
        for (int c = 0; c < 4; ++c)
            pA8[c] = Ag + (size_t)(t0 + c * 32 + srow) * K_ + xoff;
        const float* pS = ascale + ((size_t)(g * 4 + (tm >> 1)) * KB_) * 256
                        + (ptid >> 5) * 256 + (tm & 1) * 128 + (ptid & 31) * 4;

        f32x4 acc[4][4] = {};

        // ---- tile prologue: S0 + k-tiles 0,1 -> bufs 0,1 ----
        if (producer) {
            STG_S(0);
#pragma unroll
            for (int c = 0; c < 4; ++c) { STG_A(c, 0, 0); STG_B(c, 0, 0); }
#pragma unroll
            for (int c = 0; c < 4; ++c) { STG_A(c, 1, 1); STG_B(c, 1, 1); }
            asm volatile("s_waitcnt vmcnt(0)" ::: "memory");
            asm volatile("s_waitcnt lgkmcnt(0)" ::: "memory");
        }
        blockbar();

        for (int v = 0; v < NV_; ++v) {
            if (producer) {
                // ---- issue: [ascale chunk]; k-tiles 2v+2, 2v+3 ----
                if ((v & 3) == 0 && 2 * v + 8 < NT8_) STG_S((v >> 2) + 1);
                const int w0 = 2 * v + 2;
                if (w0 < NT8_) {
                    const int b0 = w0 & 3, b1 = (w0 + 1) & 3;
#pragma unroll
                    for (int c = 0; c < 4; ++c) { STG_A(c, w0, b0); STG_B(c, w0, b0); }
#pragma unroll
                    for (int c = 0; c < 4; ++c) { STG_A(c, w0 + 1, b1); STG_B(c, w0 + 1, b1); }
                }
                asm volatile("s_waitcnt vmcnt(0)" ::: "memory");
            } else {
#pragma unroll
                for (int ks = 0; ks < 2; ++ks) {
                    const int u = 2 * v + ks;
                    const int buf = u & 3;
                    const int sbuf = (u >> 3) & 1;
                    const float wsc = *(const float*)(smem + 139264 + u * 4);
                    const int abase = buf * 16384;
                    const int bbase = 65536 + buf * 16384;

#pragma unroll
                    for (int n = 0; n < 4; ++n)
                        RD_FRAG(bF[n], bbase, wcol + n * 16 + l15);
#pragma unroll
                    for (int m = 0; m < 4; ++m) {
                        const float4 sv = *(const float4*)(smem + 131072 +
                            sbuf * 4096 + (u & 7) * 512 +
                            (wrow + m * 16 + lhi * 4) * 4);
                        asv[m][0] = sv.x * wsc; asv[m][1] = sv.y * wsc;
                        asv[m][2] = sv.z * wsc; asv[m][3] = sv.w * wsc;
                    }
#pragma unroll
                    for (int m = 0; m < 4; ++m) {
                        Frag aF;
                        RD_FRAG(aF, abase, wrow + m * 16 + l15);
#pragma unroll
                        for (int n = 0; n < 4; ++n) {
                            f32x4 blk =
                                __builtin_amdgcn_mfma_scale_f32_16x16x128_f8f6f4(
                                    aF.v, bF[n].v, z4, 0, 0,
                                    0, 0x7F7F7F7F, 0, 0x7F7F7F7F);
                            acc[m][n] += blk * asv[m];
                        }
                    }
                }
            }
            blockbar();                  // publish next pair; free this pair
        }

        // ---- tile epilogue (consumers): col = lane&15, row = lhi*4 + j ----
        if (!producer) {
            float* Yg = y + (size_t)g * T_ * N_;
#pragma unroll
            for (int n = 0; n < 4; ++n) {
                const int col = n0 + wcol + n * 16 + l15;
                const float bv = bias[g * N_ + col];
#pragma unroll
                for (int m = 0; m < 4; ++m) {
                    const int r0 = t0 + wrow + m * 16 + lhi * 4;
#pragma unroll
                    for (int j = 0; j < 4; ++j)
                        Yg[(size_t)(r0 + j) * N_ + col] = acc[m][n][j] + bv;
                }
            }
        }
        // producers may already stage next tile; consumers' epilogue writes
        // overlap. Next iteration's post-prologue barrier resynchronizes.
    }
}

// ---------------------------------------------------------------------------
extern "C" void kernel_launch(void* const* d_in, const int* in_sizes, int n_in,
                              void* d_out, int out_size, void* d_ws, size_t ws_size,
                              hipStream_t stream)
{
    const float* xs     = (const float*)d_in[0];
    const float* weight = (const float*)d_in[1];
    const float* scale  = (const float*)d_in[2];
    const float* bias   = (const float*)d_in[3];
    float* y = (float*)d_out;

    uint8_t* xq8  = (uint8_t*)d_ws;                      //  58,720,256 B
    float*   ascl = (float*)((char*)d_ws + 58720256);    //   1,835,008 B
    uint8_t* wq8  = (uint8_t*)((char*)d_ws + 60555264);  // 117,440,512 B

    prep_kernel<<<ACT_WGS + WREC_WGS, 256, 0, stream>>>(
        xs, xq8, ascl, weight, wq8);

    gemm_fp8_kernel<<<256, 512, 0, stream>>>(
        xq8, wq8, ascl, scale, bias, y);
}

// Round 15
// 317.801 us; speedup vs baseline: 1.1417x; 1.1417x over previous
//
#include <hip/hip_runtime.h>
#include <hip/hip_bf16.h>
#include <stdint.h>

#define G_ 8
#define T_ 1024
#define K_ 7168
#define N_ 2048
#define KB_ 56         // K/128 quant blocks
#define NB_ 16         // N/128
#define NT8_ 56        // K-tiles of 128

#define ACT_WGS  57344   // (G*T*KB)/8
#define WREC_WGS 28672   // (G*N*K/16)/256

typedef __attribute__((ext_vector_type(4))) float f32x4;
typedef __attribute__((ext_vector_type(8))) int   i32x8;

typedef __attribute__((address_space(3))) uint32_t lds_u32_t;
typedef const __attribute__((address_space(1))) uint32_t gbl_u32_t;

__device__ __forceinline__ void gload_lds16(const void* gsrc, const void* ldst)
{
    __builtin_amdgcn_global_load_lds(
        (gbl_u32_t*)(uintptr_t)gsrc,
        (lds_u32_t*)(uint32_t)(uintptr_t)ldst, 16, 0, 0);
}

__device__ __forceinline__ void blockbar()
{
    asm volatile("" ::: "memory");
    __builtin_amdgcn_s_barrier();
    asm volatile("" ::: "memory");
}

// ---------------------------------------------------------------------------
// Kernel 1: fused prepass (verified rounds 6-14).
// ---------------------------------------------------------------------------
__global__ __launch_bounds__(256) void prep_kernel(
    const float* __restrict__ xs, uint8_t* __restrict__ xq8,
    float* __restrict__ ascale,
    const float* __restrict__ w, uint8_t* __restrict__ wq8)
{
    const int bid = blockIdx.x;
    const int tid = threadIdx.x;
    if (bid < ACT_WGS) {
        const int grp = (bid * 256 + tid) >> 5;
        const int l   = tid & 31;
        const size_t base = (size_t)grp * 128 + (size_t)l * 4;

        const float4 v = *(const float4*)(xs + base);
        float am = fmaxf(fmaxf(fabsf(v.x), fabsf(v.y)),
                         fmaxf(fabsf(v.z), fabsf(v.w)));
#pragma unroll
        for (int off = 1; off <= 16; off <<= 1)
            am = fmaxf(am, __shfl_xor(am, off, 64));

        const float rs = 448.0f / am;
        const float s  = am * (1.0f / 448.0f);

        int pk = __builtin_amdgcn_cvt_pk_fp8_f32(v.x * rs, v.y * rs, 0, false);
        pk     = __builtin_amdgcn_cvt_pk_fp8_f32(v.z * rs, v.w * rs, pk, true);
        *(uint32_t*)(xq8 + base) = (uint32_t)pk;

        if (l == 0) {
            const int kb = grp % KB_;
            const int t  = (grp / KB_) & (T_ - 1);
            const int g  = grp / (KB_ * T_);
            ascale[(((size_t)(g * 4 + (t >> 8))) * KB_ + kb) * 256 + (t & 255)] = s;
        }
    } else {
        const size_t i = ((size_t)(bid - ACT_WGS) * 256 + tid) * 16;
        uint32_t o[4];
#pragma unroll
        for (int q = 0; q < 4; ++q) {
            const float4 a = *(const float4*)(w + i + q * 4);
            int pk = __builtin_amdgcn_cvt_pk_fp8_f32(a.x, a.y, 0, false);
            pk     = __builtin_amdgcn_cvt_pk_fp8_f32(a.z, a.w, pk, true);
            o[q] = (uint32_t)pk;
        }
        *(uint4*)(wq8 + i) = make_uint4(o[0], o[1], o[2], o[3]);
    }
}

// ---------------------------------------------------------------------------
// Kernel 2: producer/consumer blockwise-fp8 grouped GEMM, 256x128 tile.
//   768 threads, 1 block/CU. Waves 0-7: consumers (4x2 grid of 64x64
//   quadrants). Waves 8-11: producers (global_load_lds, 3-deep ring,
//   r12 ledger: issue tile u+2 (12 loads), wait vmcnt(12) -> tile u+1
//   landed at the barrier, tile u+2 in flight).
//   LDS: A 3x32K @0 | B 3x16K @98304 | ascale 2x4K @147456 | ws @155648.
// ---------------------------------------------------------------------------
union Frag { i32x8 v; struct { int4 lo, hi; } p; };

#define RD_FRAG(dst, base, r)                                                 \
  { const int rx_ = ((r) & 7) << 4;                                           \
    const char* bp_ = smem + (base) + (r)*128;                                \
    dst.p.lo = *(const int4*)(bp_ + ((lhi*32) ^ rx_));                        \
    dst.p.hi = *(const int4*)(bp_ + ((lhi*32 + 16) ^ rx_)); }

#define STG_A(c, t, bb) gload_lds16(pA8[c] + (size_t)(t)*128,                 \
      smem + (bb)*32768 + (c)*4096 + ptid*16)
#define STG_B(c, t, bb) gload_lds16(pB8[c] + (size_t)(t)*128,                 \
      smem + 98304 + (bb)*16384 + (c)*4096 + ptid*16)
#define STG_S(c) gload_lds16(pS + (size_t)(c)*1024,                           \
      smem + 147456 + ((c)&1)*4096 + ptid*16)

__global__ __launch_bounds__(768, 1) void gemm_fp8_kernel(
    const uint8_t* __restrict__ xq8, const uint8_t* __restrict__ wq8,
    const float* __restrict__ ascale, const float* __restrict__ wscale,
    const float* __restrict__ bias, float* __restrict__ y)
{
    __shared__ char smem[155904];

    const int bx0 = blockIdx.x;          // 0..511
    const int g     = bx0 & 7;           // group == XCD
    const int inner = bx0 >> 3;          // 0..63
    const int tm    = inner & 3;         // 0..3 (256-row tiles)
    const int tn    = inner >> 2;        // 0..15
    const int t0 = tm * 256, n0 = tn * 128;

    const int tid  = threadIdx.x, lane = tid & 63, wid = tid >> 6;
    const bool producer = (wid >= 8);
    const int ptid = tid & 255;          // producer-local 0..255
    const int l15 = lane & 15, lhi = lane >> 4;
    const int wrow = (wid >> 1) * 64;    // consumer rows (wid 0..7 -> 0..192)
    const int wcol = (wid & 1) * 64;

    const uint8_t* Ag = xq8 + (size_t)g * T_ * K_;
    const uint8_t* Bg = wq8 + (size_t)g * N_ * K_;

    // producer staging maps: LDS(row = c*32 + ptid/8, slot = ptid&7)
    //   <- global slot ^ (row&7)
    const int srow = ptid >> 3;
    const int xoff = ((ptid & 7) ^ (srow & 7)) * 16;
    const uint8_t* pA8[8];
    const uint8_t* pB8[4];
#pragma unroll
    for (int c = 0; c < 8; ++c)
        pA8[c] = Ag + (size_t)(t0 + c * 32 + srow) * K_ + xoff;
#pragma unroll
    for (int c = 0; c < 4; ++c)
        pB8[c] = Bg + (size_t)(n0 + c * 32 + srow) * K_ + xoff;

    // ascale: [g][tb][kb][256] and tb == tm (256-row tile); chunk = 4 kb = 4KB
    const float* pS = ascale + ((size_t)(g * 4 + tm) * KB_) * 256 + ptid * 4;

    const f32x4 z4 = {0.f, 0.f, 0.f, 0.f};
    f32x4 acc[4][4] = {};
    Frag bF[4];
    f32x4 asv[4];

    // ---- prologue: wscale row, S0, tiles 0,1 -> bufs 0,1 ----
    if (producer) {
        if (ptid < KB_) {
            const float wv = wscale[((size_t)(g * NB_ + tn)) * KB_ + ptid];
            *(float*)(smem + 155648 + ptid * 4) = wv;
        }
        STG_S(0);
#pragma unroll
        for (int c = 0; c < 8; ++c) STG_A(c, 0, 0);
#pragma unroll
        for (int c = 0; c < 4; ++c) STG_B(c, 0, 0);
#pragma unroll
        for (int c = 0; c < 8; ++c) STG_A(c, 1, 1);
#pragma unroll
        for (int c = 0; c < 4; ++c) STG_B(c, 1, 1);
        asm volatile("s_waitcnt vmcnt(12)" ::: "memory");  // S0 + tile0 landed
        asm volatile("s_waitcnt lgkmcnt(0)" ::: "memory"); // wscale ds_write
    } else {
        __builtin_amdgcn_s_setprio(1);   // consumers keep MFMA priority
    }
    blockbar();

    int cur = 0;
    for (int u = 0; u < NT8_; ++u) {
        if (producer) {
            // ---- issue: [ascale chunk]; tile u+2 -> buf (cur+2)%3 ----
            if ((u & 3) == 0 && u + 4 < NT8_) STG_S((u >> 2) + 1);
            if (u + 2 < NT8_) {
                const int fb = (cur + 2 >= 3) ? cur - 1 : cur + 2;
#pragma unroll
                for (int c = 0; c < 8; ++c) STG_A(c, u + 2, fb);
#pragma unroll
                for (int c = 0; c < 4; ++c) STG_B(c, u + 2, fb);
                asm volatile("s_waitcnt vmcnt(12)" ::: "memory"); // u+1 landed
            } else if (u + 1 < NT8_) {
                asm volatile("s_waitcnt vmcnt(0)" ::: "memory");
            }
        } else {
            const float wsc = *(const float*)(smem + 155648 + u * 4);
            const int abase = cur * 32768;
            const int bbase = 98304 + cur * 16384;
            const int sbuf = (u >> 2) & 1;

            // ---- frag reads (buf cur) + rescale factors ----
#pragma unroll
            for (int n = 0; n < 4; ++n)
                RD_FRAG(bF[n], bbase, wcol + n * 16 + l15);
#pragma unroll
            for (int m = 0; m < 4; ++m) {
                const float4 sv = *(const float4*)(smem + 147456 + sbuf * 4096 +
                    (u & 3) * 1024 + (wrow + m * 16 + lhi * 4) * 4);
                asv[m][0] = sv.x * wsc; asv[m][1] = sv.y * wsc;
                asv[m][2] = sv.z * wsc; asv[m][3] = sv.w * wsc;
            }

            // ---- MFMA + rescale ----
#pragma unroll
            for (int m = 0; m < 4; ++m) {
                Frag aF;
                RD_FRAG(aF, abase, wrow + m * 16 + l15);
#pragma unroll
                for (int n = 0; n < 4; ++n) {
                    f32x4 blk = __builtin_amdgcn_mfma_scale_f32_16x16x128_f8f6f4(
                        aF.v, bF[n].v, z4, 0, 0, 0, 0x7F7F7F7F, 0, 0x7F7F7F7F);
                    acc[m][n] += blk * asv[m];
                }
            }
        }

        blockbar();                      // publish tile u+1; free buf cur
        cur = (cur + 1 >= 3) ? 0 : cur + 1;
    }

    // ---- epilogue (consumers): col = lane&15, row = (lane>>4)*4 + j ----
    if (!producer) {
        float* Yg = y + (size_t)g * T_ * N_;
#pragma unroll
        for (int n = 0; n < 4; ++n) {
            const int col = n0 + wcol + n * 16 + l15;
            const float bv = bias[g * N_ + col];
#pragma unroll
            for (int m = 0; m < 4; ++m) {
                const int r0 = t0 + wrow + m * 16 + lhi * 4;
#pragma unroll
                for (int j = 0; j < 4; ++j)
                    Yg[(size_t)(r0 + j) * N_ + col] = acc[m][n][j] + bv;
            }
        }
    }
}

// ---------------------------------------------------------------------------
extern "C" void kernel_launch(void* const* d_in, const int* in_sizes, int n_in,
                              void* d_out, int out_size, void* d_ws, size_t ws_size,
                              hipStream_t stream)
{
    const float* xs     = (const float*)d_in[0];
    const float* weight = (const float*)d_in[1];
    const float* scale  = (const float*)d_in[2];
    const float* bias   = (const float*)d_in[3];
    float* y = (float*)d_out;

    uint8_t* xq8  = (uint8_t*)d_ws;                      //  58,720,256 B
    float*   ascl = (float*)((char*)d_ws + 58720256);    //   1,835,008 B
    uint8_t* wq8  = (uint8_t*)((char*)d_ws + 60555264);  // 117,440,512 B

    prep_kernel<<<ACT_WGS + WREC_WGS, 256, 0, stream>>>(
        xs, xq8, ascl, weight, wq8);

    gemm_fp8_kernel<<<G_ * (T_ / 256) * (N_ / 128), 768, 0, stream>>>(
        xq8, wq8, ascl, scale, bias, y);
}